// Round 11
// baseline (80.716 us; speedup 1.0000x reference)
//
#include <hip/hip_runtime.h>

// spiking coESN: B=2048 samples, L=1024 steps, N_HID=1024.
// R11 = R10 (static no-spike proof, 79us) + grid-stride batching: 512 blocks
// x 4 samples/block. Unit constants (dwx/dbi/eps/gam) are sample-invariant ->
// loaded ONCE per block; per-sample work is just: 2 float4 x-loads, wave max
// reduce, closed-form bound check, zero-store (or exact replay if the proof
// fails - never for this input, absmax 0.0 across R1-R10).
// Proof (unchanged from R10, passed):
//  1) pre-first-RF-spike recurrent input is 0 => per-unit LIF drive
//     dt*I <= dtI = dt*bias + max(x,0)*dt*wx; LIF inter-spike gap >= K =
//     (1-dtI)/dtI - 1 steps.
//  2) RF pair is a damped linear oscillator: per impulse dsg, |hy| <= dsg/wd,
//     wd=sqrt(gam-eps^2/4) (checked >= 0.5/unit); envelope decay e^{-eps/2 t};
//     spikes >= K apart => max|hy| <= 1.25*dsg/(wd*(1-e^{-eps*dt*K/2})).
//  3) bound < 0.75 for all units => no RF spike possible => rf=ft=fs == 0 =>
//     output exactly zeros. Else: full exact replay from zero state.
// Data-dependent only - identical work every call (graph-capture safe).

#define NH 1024
#define LT 1024
#define SPB 4      // samples per block

__global__ __launch_bounds__(128)
void coesn_kernel(const float* __restrict__ x,      // (B, L, 1)
                  const float* __restrict__ x2h,    // (1, NH)
                  const float* __restrict__ h2h,    // (NH, NH) row-major
                  const float* __restrict__ bias,   // (NH,)
                  const float* __restrict__ gam,    // (NH,)
                  const float* __restrict__ eps,    // (NH,)
                  const float* __restrict__ sgain,  // (1,)
                  float* __restrict__ out)          // (B, 2*NH)
{
    const int tid  = threadIdx.x;     // 0..127
    const int lane = tid & 63;
    const int w    = tid >> 6;        // wave 0/1

    __shared__ float xrow[LT];                     // used by replay tier only
    __shared__ unsigned long long mskL[2][16];     // [parity][(2w+j)*4+c]
    __shared__ float wmax[2];
    __shared__ int   wbad[2];

    const float dt  = 0.01f;
    const float dsg = dt * sgain[0];      // dt * spike_gain (hz impulse size)

    // Sample-invariant per-unit constants, loaded once per block.
    // float4 index fi = (2w+j)*64 + lane; unit = (2w+j)*256 + lane*4 + c.
    float dwx[8], dbi[8], epv[8], gav[8];
    #pragma unroll
    for (int j = 0; j < 2; ++j) {
        const int fi = (2 * w + j) * 64 + lane;
        float4 t4;
        t4 = ((const float4*)x2h)[fi];
        dwx[4*j+0]=dt*t4.x; dwx[4*j+1]=dt*t4.y; dwx[4*j+2]=dt*t4.z; dwx[4*j+3]=dt*t4.w;
        t4 = ((const float4*)bias)[fi];
        dbi[4*j+0]=dt*t4.x; dbi[4*j+1]=dt*t4.y; dbi[4*j+2]=dt*t4.z; dbi[4*j+3]=dt*t4.w;
        t4 = ((const float4*)eps)[fi];
        epv[4*j+0]=t4.x; epv[4*j+1]=t4.y; epv[4*j+2]=t4.z; epv[4*j+3]=t4.w;
        t4 = ((const float4*)gam)[fi];
        gav[4*j+0]=t4.x; gav[4*j+1]=t4.y; gav[4*j+2]=t4.z; gav[4*j+3]=t4.w;
    }

    for (int it = 0; it < SPB; ++it) {
        const int b = blockIdx.x * SPB + it;

        // x[b] in registers; only staged to LDS if replay triggers.
        const float4* src = (const float4*)(x + (size_t)b * LT);
        const float4 v0 = src[tid];
        const float4 v1 = src[tid + 128];

        // Block max(x) (positive part governs the bound).
        float lm = fmaxf(fmaxf(fmaxf(v0.x, v0.y), fmaxf(v0.z, v0.w)),
                         fmaxf(fmaxf(v1.x, v1.y), fmaxf(v1.z, v1.w)));
        #pragma unroll
        for (int off = 1; off < 64; off <<= 1)
            lm = fmaxf(lm, __shfl_xor(lm, off));
        if (lane == 0) wmax[w] = lm;
        __syncthreads();
        const float mxx = fmaxf(fmaxf(wmax[0], wmax[1]), 0.0f);

        // Static no-RF-spike proof, per unit (identical to R10).
        bool ok = true;
        #pragma unroll
        for (int s = 0; s < 8; ++s) {
            const float dtI = dbi[s] + mxx * dwx[s];      // max per-step vv gain
            const float Ku  = fmaxf((1.0f - dtI) / dtI - 1.0f, 0.0f);
            const float e   = __expf(-0.5f * dt * epv[s] * Ku);
            const float wd2 = gav[s] - 0.25f * epv[s] * epv[s];
            const bool p = (dtI <= 0.0f) ||
                           ((wd2 >= 0.25f) &&
                            (1.25f * dsg < 0.75f * sqrtf(wd2) * (1.0f - e)));
            ok = ok && p;
        }
        if (lane == 0) wbad[w] = (__ballot(!ok) != 0ull) ? 1 : 0;
        __syncthreads();
        const bool bad = (wbad[0] | wbad[1]) != 0;   // block-uniform

        float* ob = out + (size_t)b * (2 * NH);

        if (!bad) {
            // No RF spike possible -> rf/ft/fs identically zero.
            const float4 z = {0.f, 0.f, 0.f, 0.f};
            #pragma unroll
            for (int j = 0; j < 2; ++j) {
                ((float4*)ob)[(2*w+j)*64 + lane]        = z;
                ((float4*)(ob + NH))[(2*w+j)*64 + lane] = z;
            }
            continue;
        }

        // ------------- COLD: full replay from zero state (exact) -----------
        {
            ((float4*)xrow)[tid]       = v0;
            ((float4*)xrow)[tid + 128] = v1;
            if (tid < 16) mskL[0][tid] = 0ull;

            const float cv  = 0.9995f;            // 1 - dt/LIF_TAU_M
            const float dcf = expf(-0.001f);      // exp(-DT/TAU_FILTER)
            const float dcr = expf(-0.04f);       // exp(-DT/TAU_REF)
            float dg[8], cez[8];
            #pragma unroll
            for (int s = 0; s < 8; ++s) {
                dg[s]  = dt * gav[s];
                cez[s] = 1.0f - dt * epv[s];
            }
            float vv[8], hz[8], hy[8], rf[8], ft[8], fs[8];
            #pragma unroll
            for (int s = 0; s < 8; ++s) {
                vv[s]=0.f; hz[s]=0.f; hy[s]=0.f; rf[s]=0.f; ft[s]=0.f; fs[s]=0.f;
            }
            const float4* h2h4 = (const float4*)h2h;
            __syncthreads();

            for (int step = 0; step < LT; ++step) {
                const int p = step & 1;
                const float xt = xrow[step];

                float a[8];
                #pragma unroll
                for (int s = 0; s < 8; ++s) a[s] = 0.f;
                // Fixed unit order: q=(2w'+j')*4+c ascending, lane ascending.
                #pragma unroll
                for (int q = 0; q < 16; ++q) {
                    unsigned long long m = mskL[p][q];
                    const int wj = q >> 2;
                    const int c  = q & 3;
                    while (m) {
                        const int l = __builtin_ctzll(m);
                        m &= (m - 1);
                        const int k = wj * 256 + l * 4 + c;     // spiked unit
                        const size_t rowb = (size_t)k * 256;
                        #pragma unroll
                        for (int j = 0; j < 2; ++j) {
                            const float4 r = h2h4[rowb + (2*w+j)*64 + lane];
                            a[4*j+0] += r.x; a[4*j+1] += r.y;
                            a[4*j+2] += r.z; a[4*j+3] += r.w;
                        }
                    }
                }

                #pragma unroll
                for (int s = 0; s < 8; ++s) {
                    float t0 = fmaf(xt, dwx[s], dbi[s]);   // dt*(xt*wx + bias)
                    t0 = fmaf(dt, a[s], t0);               // + dt * (s@h2h)
                    vv[s] = fmaf(cv, vv[s], t0);
                    const bool lc = vv[s] > 1.0f;
                    vv[s] = lc ? vv[s] - 1.0f : vv[s];
                    const float ks = lc ? dsg : 0.0f;
                    const float t1 = fmaf(-dg[s], hy[s], ks);
                    hz[s] = fmaf(cez[s], hz[s], t1);
                    hy[s] = fmaf(dt, hz[s], hy[s]);
                    const bool sc = (hy[s] - rf[s]) > 1.0f; // RF spike, old ref
                    const unsigned long long mm = __ballot(sc);
                    if (lane == 0)
                        mskL[p ^ 1][(2*w + (s >> 2)) * 4 + (s & 3)] = mm;
                    const float sn = sc ? 1.0f : 0.0f;
                    rf[s] = fmaf(dcr, rf[s], sn);
                    ft[s] = fmaf(dcf, ft[s], sn);
                    fs[s] += ft[s];
                }
                __syncthreads();   // masks visible; prev buffer reusable
            }

            const float inv = 1.0f / 1024.0f;
            #pragma unroll
            for (int j = 0; j < 2; ++j) {
                float4 mo = {fs[4*j+0]*inv, fs[4*j+1]*inv,
                             fs[4*j+2]*inv, fs[4*j+3]*inv};
                float4 to = {ft[4*j+0], ft[4*j+1], ft[4*j+2], ft[4*j+3]};
                ((float4*)ob)[(2*w+j)*64 + lane]        = mo;
                ((float4*)(ob + NH))[(2*w+j)*64 + lane] = to;
            }
        }
    }
}

extern "C" void kernel_launch(void* const* d_in, const int* in_sizes, int n_in,
                              void* d_out, int out_size, void* d_ws, size_t ws_size,
                              hipStream_t stream) {
    const float* x     = (const float*)d_in[0];
    const float* x2h   = (const float*)d_in[1];
    const float* h2h   = (const float*)d_in[2];
    const float* bias  = (const float*)d_in[3];
    const float* gam   = (const float*)d_in[4];
    const float* eps   = (const float*)d_in[5];
    const float* sgain = (const float*)d_in[6];
    float* out = (float*)d_out;

    coesn_kernel<<<dim3(2048 / SPB), dim3(128), 0, stream>>>(
        x, x2h, h2h, bias, gam, eps, sgain, out);
}